// Round 1
// 148.554 us; speedup vs baseline: 1.3164x; 1.3164x over previous
//
#include <hip/hip_runtime.h>

#define BB 2
#define CIN 64
#define CQ 32
#define DD 8
#define HH 16
#define WWW 16
#define NN 2048   // D*H*W
#define NHW 256   // H*W
#define COUT 64

#define CI_STAGE 4          // ci staged per barrier-iteration
#define XPLANE 324          // 18*18 padded plane

// ---- bias init: kbuf/qbuf/vbuf <- bias (conv kernel atomically accumulates) ----
__global__ __launch_bounds__(256) void qkv_bias_init(
    const float* __restrict__ bk, const float* __restrict__ bq, const float* __restrict__ bv,
    float* __restrict__ kout, float* __restrict__ qout, float* __restrict__ vout)
{
    int i = blockIdx.x * 256 + threadIdx.x;   // 0 .. 131071
    int co = (i >> 11) & 31;                  // (i / 2048) % 32
    kout[i] = bk[co];
    qout[i] = bq[co];
    vout[i] = bv[co];
}

// ---- fused k,q,v conv: grid 2b*8d*16co2*4cisplit = 1024 blocks, 256 threads ----
// Each block: 2 output channels x 3 convs, 16 input channels; x planes staged in
// zero-halo'd LDS (18x18); weights read via wave-uniform addresses (SGPR loads).
__global__ __launch_bounds__(256) void conv_qkv_kernel(
    const float* __restrict__ x,
    const float* __restrict__ wk, const float* __restrict__ wq, const float* __restrict__ wv,
    float* __restrict__ kout, float* __restrict__ qout, float* __restrict__ vout)
{
    int bid   = blockIdx.x;
    int split = bid & 3;
    int co2   = (bid >> 2) & 15;
    int d     = (bid >> 6) & 7;
    int b     = bid >> 9;
    int co0   = co2 << 1;
    int ci0   = split << 4;    // 16 ci per split

    __shared__ float xl[CI_STAGE * 3 * XPLANE];

    int tid = threadIdx.x;
    // zero once: halo stays zero forever (interior-only rewrites)
    for (int i = tid; i < CI_STAGE * 3 * XPLANE; i += 256) xl[i] = 0.f;

    int h  = tid >> 4;
    int w  = tid & 15;
    int wr = (h + 1) * 18 + (w + 1);   // interior store offset
    int rb = h * 18 + w;               // read base: tap (kh,kw) at rb + kh*18 + kw

    float a0 = 0.f, a1 = 0.f, a2 = 0.f, a3 = 0.f, a4 = 0.f, a5 = 0.f;

    const float* xb = x + ((size_t)b * CIN + ci0) * NN;

    #pragma unroll 1
    for (int it = 0; it < 16; it += CI_STAGE) {
        __syncthreads();
        #pragma unroll
        for (int kd = 0; kd < 3; ++kd) {
            int dd = d + kd - 1;
            if (dd >= 0 && dd < DD) {          // block-uniform branch
                #pragma unroll
                for (int cc = 0; cc < CI_STAGE; ++cc)
                    xl[(cc * 3 + kd) * XPLANE + wr] =
                        xb[(size_t)(it + cc) * NN + dd * NHW + tid];
            }
        }
        __syncthreads();

        for (int cc = 0; cc < CI_STAGE; ++cc) {
            int ci = ci0 + it + cc;
            // wave-uniform weight rows -> scalar loads (SGPR operands to the FMAs)
            const float* wk0 = wk + ((size_t)co0 * CIN + ci) * 27;
            const float* wk1 = wk0 + (size_t)CIN * 27;
            const float* wq0 = wq + ((size_t)co0 * CIN + ci) * 27;
            const float* wq1 = wq0 + (size_t)CIN * 27;
            const float* wv0 = wv + ((size_t)co0 * CIN + ci) * 27;
            const float* wv1 = wv0 + (size_t)CIN * 27;
            const float* xp  = xl + cc * 3 * XPLANE + rb;
            #pragma unroll
            for (int kd = 0; kd < 3; ++kd) {
                int dd = d + kd - 1;
                if (dd < 0 || dd >= DD) continue;   // block-uniform
                #pragma unroll
                for (int kh = 0; kh < 3; ++kh) {
                    #pragma unroll
                    for (int kw = 0; kw < 3; ++kw) {
                        float xv = xp[kd * XPLANE + kh * 18 + kw];
                        int t = kd * 9 + kh * 3 + kw;
                        a0 = fmaf(xv, wk0[t], a0);
                        a1 = fmaf(xv, wk1[t], a1);
                        a2 = fmaf(xv, wq0[t], a2);
                        a3 = fmaf(xv, wq1[t], a3);
                        a4 = fmaf(xv, wv0[t], a4);
                        a5 = fmaf(xv, wv1[t], a5);
                    }
                }
            }
        }
    }

    size_t o0 = ((size_t)b * CQ + co0) * NN + d * NHW + tid;
    unsafeAtomicAdd(&kout[o0],      a0);
    unsafeAtomicAdd(&kout[o0 + NN], a1);
    unsafeAtomicAdd(&qout[o0],      a2);
    unsafeAtomicAdd(&qout[o0 + NN], a3);
    unsafeAtomicAdd(&vout[o0],      a4);
    unsafeAtomicAdd(&vout[o0 + NN], a5);
}

// ---- partial softmax column stats: grid 32c*8mtile*4nchunk = 1024 blocks ----
// pmax/psum layout: [c][nchunk][m]  (32*4*2048)
__global__ __launch_bounds__(256) void mz_partial_kernel(
    const float* __restrict__ kbuf, const float* __restrict__ qbuf,
    float* __restrict__ pmax, float* __restrict__ psum)
{
    int bid = blockIdx.x;
    int nchunk = bid & 3;
    int mtile  = (bid >> 2) & 7;
    int c      = bid >> 5;

    __shared__ float q0l[512], q1l[512];
    int tid = threadIdx.x;
    int n0 = nchunk * 512;
    q0l[tid]       = qbuf[(size_t)c * NN + n0 + tid];
    q0l[tid + 256] = qbuf[(size_t)c * NN + n0 + tid + 256];
    q1l[tid]       = qbuf[(size_t)(CQ + c) * NN + n0 + tid];
    q1l[tid + 256] = qbuf[(size_t)(CQ + c) * NN + n0 + tid + 256];
    __syncthreads();

    int m = mtile * 256 + tid;
    float k0 = kbuf[(size_t)c * NN + m];
    float k1 = kbuf[(size_t)(CQ + c) * NN + m];

    const float4* q0v = (const float4*)q0l;
    const float4* q1v = (const float4*)q1l;

    float mx0 = -1e30f, mx1 = -1e30f;
    #pragma unroll 4
    for (int i = 0; i < 128; ++i) {
        float4 a = q0v[i], b = q1v[i];
        float s0 = fmaf(k0, a.x, k1 * b.x);
        float s1 = fmaf(k0, a.y, k1 * b.y);
        float s2 = fmaf(k0, a.z, k1 * b.z);
        float s3 = fmaf(k0, a.w, k1 * b.w);
        mx0 = fmaxf(mx0, fmaxf(s0, s1));
        mx1 = fmaxf(mx1, fmaxf(s2, s3));
    }
    float mx = fmaxf(mx0, mx1);

    float z0 = 0.f, z1 = 0.f;
    #pragma unroll 4
    for (int i = 0; i < 128; ++i) {
        float4 a = q0v[i], b = q1v[i];
        float s0 = fmaf(k0, a.x, k1 * b.x);
        float s1 = fmaf(k0, a.y, k1 * b.y);
        float s2 = fmaf(k0, a.z, k1 * b.z);
        float s3 = fmaf(k0, a.w, k1 * b.w);
        z0 += __expf(s0 - mx) + __expf(s1 - mx);
        z1 += __expf(s2 - mx) + __expf(s3 - mx);
    }
    size_t o = ((size_t)c * 4 + nchunk) * NN + m;
    pmax[o] = mx;
    psum[o] = z0 + z1;
}

// ---- attention apply partial: grid 32c*8ntile*4mchunk = 1024 blocks ----
// parts layout: 4 buffers of [c][n][b] (131072 each)
__global__ __launch_bounds__(256) void att_partial_kernel(
    const float* __restrict__ kbuf, const float* __restrict__ qbuf,
    const float* __restrict__ vbuf,
    const float* __restrict__ pmax, const float* __restrict__ psum,
    float* __restrict__ parts)
{
    int bid = blockIdx.x;
    int mchunk = bid & 3;
    int ntile  = (bid >> 2) & 7;
    int c      = bid >> 5;

    __shared__ float k0l[512], k1l[512], vz0[512], vz1[512], Ml[512];
    int tid = threadIdx.x;
    for (int i = tid; i < 512; i += 256) {
        int m = mchunk * 512 + i;
        float p0 = pmax[((size_t)c * 4 + 0) * NN + m];
        float p1 = pmax[((size_t)c * 4 + 1) * NN + m];
        float p2 = pmax[((size_t)c * 4 + 2) * NN + m];
        float p3 = pmax[((size_t)c * 4 + 3) * NN + m];
        float M = fmaxf(fmaxf(p0, p1), fmaxf(p2, p3));
        float z = psum[((size_t)c * 4 + 0) * NN + m] * __expf(p0 - M)
                + psum[((size_t)c * 4 + 1) * NN + m] * __expf(p1 - M)
                + psum[((size_t)c * 4 + 2) * NN + m] * __expf(p2 - M)
                + psum[((size_t)c * 4 + 3) * NN + m] * __expf(p3 - M);
        float rz = 1.f / z;   // z >= 1 always
        k0l[i] = kbuf[(size_t)c * NN + m];
        k1l[i] = kbuf[(size_t)(CQ + c) * NN + m];
        vz0[i] = vbuf[(size_t)c * NN + m] * rz;
        vz1[i] = vbuf[(size_t)(CQ + c) * NN + m] * rz;
        Ml[i]  = M;
    }
    __syncthreads();

    int n = ntile * 256 + tid;
    float q0 = qbuf[(size_t)c * NN + n];
    float q1 = qbuf[(size_t)(CQ + c) * NN + n];

    const float4* k0v = (const float4*)k0l;
    const float4* k1v = (const float4*)k1l;
    const float4* v0v = (const float4*)vz0;
    const float4* v1v = (const float4*)vz1;
    const float4* Mv  = (const float4*)Ml;

    float a0 = 0.f, a1 = 0.f;
    #pragma unroll 4
    for (int i = 0; i < 128; ++i) {
        float4 kk0 = k0v[i], kk1 = k1v[i], mm = Mv[i], w0 = v0v[i], w1 = v1v[i];
        float e;
        e = __expf(fmaf(q0, kk0.x, q1 * kk1.x) - mm.x);
        a0 = fmaf(e, w0.x, a0); a1 = fmaf(e, w1.x, a1);
        e = __expf(fmaf(q0, kk0.y, q1 * kk1.y) - mm.y);
        a0 = fmaf(e, w0.y, a0); a1 = fmaf(e, w1.y, a1);
        e = __expf(fmaf(q0, kk0.z, q1 * kk1.z) - mm.z);
        a0 = fmaf(e, w0.z, a0); a1 = fmaf(e, w1.z, a1);
        e = __expf(fmaf(q0, kk0.w, q1 * kk1.w) - mm.w);
        a0 = fmaf(e, w0.w, a0); a1 = fmaf(e, w1.w, a1);
    }
    float* dst = parts + (size_t)mchunk * (CQ * NN * BB);
    dst[((size_t)c * NN + n) * BB + 0] = a0;
    dst[((size_t)c * NN + n) * BB + 1] = a1;
}

// ---- sum 4 partials -> ybuf: grid 128 blocks ----
__global__ __launch_bounds__(256) void combine_kernel(
    const float* __restrict__ parts, float* __restrict__ ybuf)
{
    int i = blockIdx.x * 256 + threadIdx.x;   // float4 index, 32768 total
    const float4* p0 = (const float4*)parts;
    const float4* p1 = (const float4*)(parts + CQ * NN * BB);
    const float4* p2 = (const float4*)(parts + 2 * CQ * NN * BB);
    const float4* p3 = (const float4*)(parts + 3 * CQ * NN * BB);
    float4 a = p0[i], b = p1[i], c = p2[i], d = p3[i];
    float4 r;
    r.x = a.x + b.x + c.x + d.x;
    r.y = a.y + b.y + c.y + d.y;
    r.z = a.z + b.z + c.z + d.z;
    r.w = a.w + b.w + c.w + d.w;
    ((float4*)ybuf)[i] = r;
}

// ---- final conv (32->64) + bias + residual: grid 2*64*8 = 1024 blocks ----
__global__ __launch_bounds__(256) void conv_out_kernel(
    const float* __restrict__ ybuf,
    const float* __restrict__ wa, const float* __restrict__ ba,
    const float* __restrict__ x, float* __restrict__ out)
{
    int bid = blockIdx.x;
    int d  = bid & 7;
    int co = (bid >> 3) & 63;
    int b  = bid >> 9;

    __shared__ float wl[CQ * 27];
    for (int i = threadIdx.x; i < CQ * 27; i += 256)
        wl[i] = wa[co * CQ * 27 + i];
    __syncthreads();

    int tid = threadIdx.x;
    int h = tid >> 4;
    int w = tid & 15;

    float acc = ba[co];
    for (int ci = 0; ci < CQ; ++ci) {
        // ybuf ([C,N,B] flat) reinterpreted as [B][32][2048]
        const float* y0 = ybuf + (size_t)b * CQ * NN + (size_t)ci * NN;
        const float* wp = wl + ci * 27;
        #pragma unroll
        for (int kd = 0; kd < 3; ++kd) {
            int dd = d + kd - 1;
            if (dd < 0 || dd >= DD) continue;
            int off_d = dd * NHW;
            #pragma unroll
            for (int kh = 0; kh < 3; ++kh) {
                int hh = h + kh - 1;
                bool hok = (hh >= 0) && (hh < HH);
                int off = off_d + hh * WWW;
                #pragma unroll
                for (int kw = 0; kw < 3; ++kw) {
                    int ww = w + kw - 1;
                    bool ok = hok && (ww >= 0) && (ww < WWW);
                    float yv = ok ? y0[off + ww] : 0.f;
                    acc = fmaf(yv, wp[kd * 9 + kh * 3 + kw], acc);
                }
            }
        }
    }
    size_t oi = ((size_t)b * COUT + co) * NN + d * NHW + tid;
    out[oi] = x[oi] + acc;
}

extern "C" void kernel_launch(void* const* d_in, const int* in_sizes, int n_in,
                              void* d_out, int out_size, void* d_ws, size_t ws_size,
                              hipStream_t stream) {
    const float* x  = (const float*)d_in[0];
    const float* wk = (const float*)d_in[1];
    const float* bk = (const float*)d_in[2];
    const float* wq = (const float*)d_in[3];
    const float* bq = (const float*)d_in[4];
    const float* wv = (const float*)d_in[5];
    const float* bv = (const float*)d_in[6];
    const float* wa = (const float*)d_in[7];
    const float* ba = (const float*)d_in[8];
    float* out = (float*)d_out;

    float* ws   = (float*)d_ws;
    float* kbuf = ws;                        // [2][32][2048]        131072
    float* qbuf = kbuf + BB * CQ * NN;       // [2][32][2048]        131072
    float* vbuf = qbuf + BB * CQ * NN;       // [2][32][2048]        131072
    float* pmax = vbuf + BB * CQ * NN;       // [32][4][2048]        262144
    float* psum = pmax + CQ * 4 * NN;        // [32][4][2048]        262144
    float* parts = psum + CQ * 4 * NN;       // 4 x [32][2048][2]    524288
    float* ybuf = kbuf;                      // alias: kbuf dead after att

    qkv_bias_init<<<512, 256, 0, stream>>>(bk, bq, bv, kbuf, qbuf, vbuf);
    conv_qkv_kernel<<<1024, 256, 0, stream>>>(x, wk, wq, wv, kbuf, qbuf, vbuf);
    mz_partial_kernel<<<1024, 256, 0, stream>>>(kbuf, qbuf, pmax, psum);
    att_partial_kernel<<<1024, 256, 0, stream>>>(kbuf, qbuf, vbuf, pmax, psum, parts);
    combine_kernel<<<128, 256, 0, stream>>>(parts, ybuf);
    conv_out_kernel<<<1024, 256, 0, stream>>>(ybuf, wa, ba, x, out);
}

// Round 2
// 113.241 us; speedup vs baseline: 1.7270x; 1.3118x over previous
//
#include <hip/hip_runtime.h>

#define BB 2
#define CIN 64
#define CQ 32
#define DD 8
#define HH 16
#define WWW 16
#define NN 2048   // D*H*W
#define NHW 256   // H*W
#define COUT 64

#define CI_STAGE 4          // ci staged per barrier-iteration
#define XPLANE 324          // 18*18 padded plane

// ---- init: qkv bufs <- bias ; out <- x + bias (conv kernels atomically accumulate) ----
__global__ __launch_bounds__(256) void init_kernel(
    const float* __restrict__ bk, const float* __restrict__ bq, const float* __restrict__ bv,
    const float* __restrict__ ba, const float* __restrict__ x,
    float* __restrict__ kout, float* __restrict__ qout, float* __restrict__ vout,
    float* __restrict__ out)
{
    int i = blockIdx.x * 256 + threadIdx.x;   // 0 .. 393215
    if (i < BB * CQ * NN) {
        int co = (i >> 11) & 31;
        kout[i] = bk[co];
        qout[i] = bq[co];
        vout[i] = bv[co];
    } else {
        int j = i - BB * CQ * NN;             // 0 .. 262143
        int co = (j >> 11) & 63;
        out[j] = x[j] + ba[co];
    }
}

// ---- fused k,q,v conv: grid 2b*8d*16co2*4cisplit = 1024 blocks, 256 threads ----
// Each block: 2 output channels x 3 convs, 16 input channels; x planes staged in
// zero-halo'd LDS (18x18); weights read via wave-uniform addresses (SGPR loads).
__global__ __launch_bounds__(256) void conv_qkv_kernel(
    const float* __restrict__ x,
    const float* __restrict__ wk, const float* __restrict__ wq, const float* __restrict__ wv,
    float* __restrict__ kout, float* __restrict__ qout, float* __restrict__ vout)
{
    int bid   = blockIdx.x;
    int split = bid & 3;
    int co2   = (bid >> 2) & 15;
    int d     = (bid >> 6) & 7;
    int b     = bid >> 9;
    int co0   = co2 << 1;
    int ci0   = split << 4;    // 16 ci per split

    __shared__ float xl[CI_STAGE * 3 * XPLANE];

    int tid = threadIdx.x;
    // zero once: halo stays zero forever (interior-only rewrites)
    for (int i = tid; i < CI_STAGE * 3 * XPLANE; i += 256) xl[i] = 0.f;

    int h  = tid >> 4;
    int w  = tid & 15;
    int wr = (h + 1) * 18 + (w + 1);   // interior store offset
    int rb = h * 18 + w;               // read base: tap (kh,kw) at rb + kh*18 + kw

    float a0 = 0.f, a1 = 0.f, a2 = 0.f, a3 = 0.f, a4 = 0.f, a5 = 0.f;

    const float* xb = x + ((size_t)b * CIN + ci0) * NN;

    #pragma unroll 1
    for (int it = 0; it < 16; it += CI_STAGE) {
        __syncthreads();
        #pragma unroll
        for (int kd = 0; kd < 3; ++kd) {
            int dd = d + kd - 1;
            if (dd >= 0 && dd < DD) {          // block-uniform branch
                #pragma unroll
                for (int cc = 0; cc < CI_STAGE; ++cc)
                    xl[(cc * 3 + kd) * XPLANE + wr] =
                        xb[(size_t)(it + cc) * NN + dd * NHW + tid];
            }
        }
        __syncthreads();

        for (int cc = 0; cc < CI_STAGE; ++cc) {
            int ci = ci0 + it + cc;
            // wave-uniform weight rows -> scalar loads (SGPR operands to the FMAs)
            const float* wk0 = wk + ((size_t)co0 * CIN + ci) * 27;
            const float* wk1 = wk0 + (size_t)CIN * 27;
            const float* wq0 = wq + ((size_t)co0 * CIN + ci) * 27;
            const float* wq1 = wq0 + (size_t)CIN * 27;
            const float* wv0 = wv + ((size_t)co0 * CIN + ci) * 27;
            const float* wv1 = wv0 + (size_t)CIN * 27;
            const float* xp  = xl + cc * 3 * XPLANE + rb;
            #pragma unroll
            for (int kd = 0; kd < 3; ++kd) {
                int dd = d + kd - 1;
                if (dd < 0 || dd >= DD) continue;   // block-uniform
                #pragma unroll
                for (int kh = 0; kh < 3; ++kh) {
                    #pragma unroll
                    for (int kw = 0; kw < 3; ++kw) {
                        float xv = xp[kd * XPLANE + kh * 18 + kw];
                        int t = kd * 9 + kh * 3 + kw;
                        a0 = fmaf(xv, wk0[t], a0);
                        a1 = fmaf(xv, wk1[t], a1);
                        a2 = fmaf(xv, wq0[t], a2);
                        a3 = fmaf(xv, wq1[t], a3);
                        a4 = fmaf(xv, wv0[t], a4);
                        a5 = fmaf(xv, wv1[t], a5);
                    }
                }
            }
        }
    }

    size_t o0 = ((size_t)b * CQ + co0) * NN + d * NHW + tid;
    unsafeAtomicAdd(&kout[o0],      a0);
    unsafeAtomicAdd(&kout[o0 + NN], a1);
    unsafeAtomicAdd(&qout[o0],      a2);
    unsafeAtomicAdd(&qout[o0 + NN], a3);
    unsafeAtomicAdd(&vout[o0],      a4);
    unsafeAtomicAdd(&vout[o0 + NN], a5);
}

// ---- partial softmax column stats: grid 32c*8mtile*4nchunk = 1024 blocks ----
// pmax/psum layout: [c][nchunk][m]  (32*4*2048)
__global__ __launch_bounds__(256) void mz_partial_kernel(
    const float* __restrict__ kbuf, const float* __restrict__ qbuf,
    float* __restrict__ pmax, float* __restrict__ psum)
{
    int bid = blockIdx.x;
    int nchunk = bid & 3;
    int mtile  = (bid >> 2) & 7;
    int c      = bid >> 5;

    __shared__ float q0l[512], q1l[512];
    int tid = threadIdx.x;
    int n0 = nchunk * 512;
    q0l[tid]       = qbuf[(size_t)c * NN + n0 + tid];
    q0l[tid + 256] = qbuf[(size_t)c * NN + n0 + tid + 256];
    q1l[tid]       = qbuf[(size_t)(CQ + c) * NN + n0 + tid];
    q1l[tid + 256] = qbuf[(size_t)(CQ + c) * NN + n0 + tid + 256];
    __syncthreads();

    int m = mtile * 256 + tid;
    float k0 = kbuf[(size_t)c * NN + m];
    float k1 = kbuf[(size_t)(CQ + c) * NN + m];

    const float4* q0v = (const float4*)q0l;
    const float4* q1v = (const float4*)q1l;

    float mx0 = -1e30f, mx1 = -1e30f;
    #pragma unroll 4
    for (int i = 0; i < 128; ++i) {
        float4 a = q0v[i], b = q1v[i];
        float s0 = fmaf(k0, a.x, k1 * b.x);
        float s1 = fmaf(k0, a.y, k1 * b.y);
        float s2 = fmaf(k0, a.z, k1 * b.z);
        float s3 = fmaf(k0, a.w, k1 * b.w);
        mx0 = fmaxf(mx0, fmaxf(s0, s1));
        mx1 = fmaxf(mx1, fmaxf(s2, s3));
    }
    float mx = fmaxf(mx0, mx1);

    float z0 = 0.f, z1 = 0.f;
    #pragma unroll 4
    for (int i = 0; i < 128; ++i) {
        float4 a = q0v[i], b = q1v[i];
        float s0 = fmaf(k0, a.x, k1 * b.x);
        float s1 = fmaf(k0, a.y, k1 * b.y);
        float s2 = fmaf(k0, a.z, k1 * b.z);
        float s3 = fmaf(k0, a.w, k1 * b.w);
        z0 += __expf(s0 - mx) + __expf(s1 - mx);
        z1 += __expf(s2 - mx) + __expf(s3 - mx);
    }
    size_t o = ((size_t)c * 4 + nchunk) * NN + m;
    pmax[o] = mx;
    psum[o] = z0 + z1;
}

// ---- attention apply partial: grid 32c*8ntile*4mchunk = 1024 blocks ----
// parts layout: 4 buffers of [c][n][b] (131072 each)
__global__ __launch_bounds__(256) void att_partial_kernel(
    const float* __restrict__ kbuf, const float* __restrict__ qbuf,
    const float* __restrict__ vbuf,
    const float* __restrict__ pmax, const float* __restrict__ psum,
    float* __restrict__ parts)
{
    int bid = blockIdx.x;
    int mchunk = bid & 3;
    int ntile  = (bid >> 2) & 7;
    int c      = bid >> 5;

    __shared__ float k0l[512], k1l[512], vz0[512], vz1[512], Ml[512];
    int tid = threadIdx.x;
    for (int i = tid; i < 512; i += 256) {
        int m = mchunk * 512 + i;
        float p0 = pmax[((size_t)c * 4 + 0) * NN + m];
        float p1 = pmax[((size_t)c * 4 + 1) * NN + m];
        float p2 = pmax[((size_t)c * 4 + 2) * NN + m];
        float p3 = pmax[((size_t)c * 4 + 3) * NN + m];
        float M = fmaxf(fmaxf(p0, p1), fmaxf(p2, p3));
        float z = psum[((size_t)c * 4 + 0) * NN + m] * __expf(p0 - M)
                + psum[((size_t)c * 4 + 1) * NN + m] * __expf(p1 - M)
                + psum[((size_t)c * 4 + 2) * NN + m] * __expf(p2 - M)
                + psum[((size_t)c * 4 + 3) * NN + m] * __expf(p3 - M);
        float rz = 1.f / z;   // z >= 1 always
        k0l[i] = kbuf[(size_t)c * NN + m];
        k1l[i] = kbuf[(size_t)(CQ + c) * NN + m];
        vz0[i] = vbuf[(size_t)c * NN + m] * rz;
        vz1[i] = vbuf[(size_t)(CQ + c) * NN + m] * rz;
        Ml[i]  = M;
    }
    __syncthreads();

    int n = ntile * 256 + tid;
    float q0 = qbuf[(size_t)c * NN + n];
    float q1 = qbuf[(size_t)(CQ + c) * NN + n];

    const float4* k0v = (const float4*)k0l;
    const float4* k1v = (const float4*)k1l;
    const float4* v0v = (const float4*)vz0;
    const float4* v1v = (const float4*)vz1;
    const float4* Mv  = (const float4*)Ml;

    float a0 = 0.f, a1 = 0.f;
    #pragma unroll 4
    for (int i = 0; i < 128; ++i) {
        float4 kk0 = k0v[i], kk1 = k1v[i], mm = Mv[i], w0 = v0v[i], w1 = v1v[i];
        float e;
        e = __expf(fmaf(q0, kk0.x, q1 * kk1.x) - mm.x);
        a0 = fmaf(e, w0.x, a0); a1 = fmaf(e, w1.x, a1);
        e = __expf(fmaf(q0, kk0.y, q1 * kk1.y) - mm.y);
        a0 = fmaf(e, w0.y, a0); a1 = fmaf(e, w1.y, a1);
        e = __expf(fmaf(q0, kk0.z, q1 * kk1.z) - mm.z);
        a0 = fmaf(e, w0.z, a0); a1 = fmaf(e, w1.z, a1);
        e = __expf(fmaf(q0, kk0.w, q1 * kk1.w) - mm.w);
        a0 = fmaf(e, w0.w, a0); a1 = fmaf(e, w1.w, a1);
    }
    float* dst = parts + (size_t)mchunk * (CQ * NN * BB);
    dst[((size_t)c * NN + n) * BB + 0] = a0;
    dst[((size_t)c * NN + n) * BB + 1] = a1;
}

// ---- sum 4 partials -> ybuf: grid 128 blocks ----
__global__ __launch_bounds__(256) void combine_kernel(
    const float* __restrict__ parts, float* __restrict__ ybuf)
{
    int i = blockIdx.x * 256 + threadIdx.x;   // float4 index, 32768 total
    const float4* p0 = (const float4*)parts;
    const float4* p1 = (const float4*)(parts + CQ * NN * BB);
    const float4* p2 = (const float4*)(parts + 2 * CQ * NN * BB);
    const float4* p3 = (const float4*)(parts + 3 * CQ * NN * BB);
    float4 a = p0[i], b = p1[i], c = p2[i], d = p3[i];
    float4 r;
    r.x = a.x + b.x + c.x + d.x;
    r.y = a.y + b.y + c.y + d.y;
    r.z = a.z + b.z + c.z + d.z;
    r.w = a.w + b.w + c.w + d.w;
    ((float4*)ybuf)[i] = r;
}

// ---- final conv (32->64): grid 2b*8d*16cog*4cisplit = 1024 blocks ----
// 4 output channels per block, 8 input channels; y planes staged in zero-halo'd
// LDS; weights via wave-uniform addresses (SGPR); accumulate into pre-initialized
// out (= x + bias) with atomics.
__global__ __launch_bounds__(256) void conv_out_kernel(
    const float* __restrict__ ybuf,
    const float* __restrict__ wa,
    float* __restrict__ out)
{
    int bid   = blockIdx.x;
    int split = bid & 3;
    int cog   = (bid >> 2) & 15;
    int d     = (bid >> 6) & 7;
    int b     = bid >> 9;
    int co0   = cog << 2;
    int ci0   = split << 3;   // 8 ci per split

    __shared__ float yl[CI_STAGE * 3 * XPLANE];

    int tid = threadIdx.x;
    for (int i = tid; i < CI_STAGE * 3 * XPLANE; i += 256) yl[i] = 0.f;

    int h  = tid >> 4;
    int w  = tid & 15;
    int wr = (h + 1) * 18 + (w + 1);
    int rb = h * 18 + w;

    float a0 = 0.f, a1 = 0.f, a2 = 0.f, a3 = 0.f;

    // ybuf ([C,N,B] flat) reinterpreted as [B][32][2048]
    const float* yb = ybuf + ((size_t)b * CQ + ci0) * NN;

    #pragma unroll 1
    for (int it = 0; it < 8; it += CI_STAGE) {
        __syncthreads();
        #pragma unroll
        for (int kd = 0; kd < 3; ++kd) {
            int dd = d + kd - 1;
            if (dd >= 0 && dd < DD) {          // block-uniform branch
                #pragma unroll
                for (int cc = 0; cc < CI_STAGE; ++cc)
                    yl[(cc * 3 + kd) * XPLANE + wr] =
                        yb[(size_t)(it + cc) * NN + dd * NHW + tid];
            }
        }
        __syncthreads();

        for (int cc = 0; cc < CI_STAGE; ++cc) {
            int ci = ci0 + it + cc;
            const float* w0 = wa + ((size_t)(co0 + 0) * CQ + ci) * 27;
            const float* w1 = wa + ((size_t)(co0 + 1) * CQ + ci) * 27;
            const float* w2 = wa + ((size_t)(co0 + 2) * CQ + ci) * 27;
            const float* w3 = wa + ((size_t)(co0 + 3) * CQ + ci) * 27;
            const float* yp = yl + cc * 3 * XPLANE + rb;
            #pragma unroll
            for (int kd = 0; kd < 3; ++kd) {
                int dd = d + kd - 1;
                if (dd < 0 || dd >= DD) continue;   // block-uniform
                #pragma unroll
                for (int kh = 0; kh < 3; ++kh) {
                    #pragma unroll
                    for (int kw = 0; kw < 3; ++kw) {
                        float yv = yp[kd * XPLANE + kh * 18 + kw];
                        int t = kd * 9 + kh * 3 + kw;
                        a0 = fmaf(yv, w0[t], a0);
                        a1 = fmaf(yv, w1[t], a1);
                        a2 = fmaf(yv, w2[t], a2);
                        a3 = fmaf(yv, w3[t], a3);
                    }
                }
            }
        }
    }

    size_t o = ((size_t)b * COUT + co0) * NN + d * NHW + tid;
    unsafeAtomicAdd(&out[o],          a0);
    unsafeAtomicAdd(&out[o + NN],     a1);
    unsafeAtomicAdd(&out[o + 2 * NN], a2);
    unsafeAtomicAdd(&out[o + 3 * NN], a3);
}

extern "C" void kernel_launch(void* const* d_in, const int* in_sizes, int n_in,
                              void* d_out, int out_size, void* d_ws, size_t ws_size,
                              hipStream_t stream) {
    const float* x  = (const float*)d_in[0];
    const float* wk = (const float*)d_in[1];
    const float* bk = (const float*)d_in[2];
    const float* wq = (const float*)d_in[3];
    const float* bq = (const float*)d_in[4];
    const float* wv = (const float*)d_in[5];
    const float* bv = (const float*)d_in[6];
    const float* wa = (const float*)d_in[7];
    const float* ba = (const float*)d_in[8];
    float* out = (float*)d_out;

    float* ws   = (float*)d_ws;
    float* kbuf = ws;                        // [2][32][2048]        131072
    float* qbuf = kbuf + BB * CQ * NN;       // [2][32][2048]        131072
    float* vbuf = qbuf + BB * CQ * NN;       // [2][32][2048]        131072
    float* pmax = vbuf + BB * CQ * NN;       // [32][4][2048]        262144
    float* psum = pmax + CQ * 4 * NN;        // [32][4][2048]        262144
    float* parts = psum + CQ * 4 * NN;       // 4 x [32][2048][2]    524288
    float* ybuf = kbuf;                      // alias: kbuf dead after att

    init_kernel<<<1536, 256, 0, stream>>>(bk, bq, bv, ba, x, kbuf, qbuf, vbuf, out);
    conv_qkv_kernel<<<1024, 256, 0, stream>>>(x, wk, wq, wv, kbuf, qbuf, vbuf);
    mz_partial_kernel<<<1024, 256, 0, stream>>>(kbuf, qbuf, pmax, psum);
    att_partial_kernel<<<1024, 256, 0, stream>>>(kbuf, qbuf, vbuf, pmax, psum, parts);
    combine_kernel<<<128, 256, 0, stream>>>(parts, ybuf);
    conv_out_kernel<<<1024, 256, 0, stream>>>(ybuf, wa, out);
}